// Round 4
// baseline (303.336 us; speedup 1.0000x reference)
//
#include <hip/hip_runtime.h>
#include <hip/hip_bf16.h>

#define NN 25000
#define NE 100000
#define FIN 32
#define DD 64
#define NG 1000

typedef unsigned short u16;
typedef __attribute__((ext_vector_type(8))) short short8;
typedef __attribute__((ext_vector_type(4))) float f32x4;

__device__ __forceinline__ float b2f(u16 u) {
    union { unsigned int i; float f; } v; v.i = ((unsigned int)u) << 16; return v.f;
}
__device__ __forceinline__ u16 f2b(float f) {
    __hip_bfloat16 h = __float2bfloat16(f);
    return __builtin_bit_cast(u16, h);
}
// edge_index may be int64 read as int32 words: odd words would all be 0.
__device__ __forceinline__ bool idx_is_i64(const int* e) {
    return (e[1] == 0) & (e[3] == 0) & (e[5] == 0) & (e[7] == 0) & (e[9] == 0);
}
__device__ __forceinline__ int ld_src(const int* e, int i, bool i64) {
    return i64 ? e[2 * i] : e[i];
}
__device__ __forceinline__ int ld_dst(const int* e, int i, bool i64) {
    return i64 ? e[2 * (NE + i)] : e[NE + i];
}

// ---- fused pre-pass: blocks [0,1563) = lin0 (16 rows/block); [1563,2587) = Bt2 + zero ----
// CSR mode additionally histograms edge dst into cur[] (int atomics).
// Bt2 fragment-major: idx = kc*4096 + (s*4+c)*512 + lane*8 + j  holds
// B[k = kc*64 + s*32 + (lane>>4)*8 + j][o = c*16 + (lane&15)]  (r>=4096 -> be2 rows).
__global__ __launch_bounds__(256) void k_pre(const float* __restrict__ x,
                                             const float* __restrict__ W0,
                                             const float* __restrict__ b0,
                                             u16* __restrict__ x1b,
                                             const float* __restrict__ We2,
                                             const float* __restrict__ be2,
                                             float* __restrict__ agg,
                                             float* __restrict__ pooled,
                                             u16* __restrict__ Bt2,
                                             const int* __restrict__ eidx,
                                             int* __restrict__ cur,
                                             int use_csr) {
    __shared__ float sW[FIN * DD];
    __shared__ float sx[16 * FIN];
    if (blockIdx.x < 1563) {
        int tid = threadIdx.x;
        for (int i = tid; i < FIN * DD; i += 256) sW[i] = W0[i];
        int nbase = blockIdx.x * 16;
        for (int i = tid; i < 16 * FIN; i += 256) {
            int nl = i >> 5, f = i & 31;
            int n = nbase + nl;
            sx[i] = (n < NN) ? x[n * FIN + f] : 0.f;
        }
        __syncthreads();
        int lane = tid & 63, nl = tid >> 6;
        float bias = b0[lane];
        #pragma unroll
        for (int rr = 0; rr < 4; rr++) {
            int row = nl * 4 + rr;
            int n = nbase + row;
            if (n < NN) {
                float acc = bias;
                #pragma unroll
                for (int f = 0; f < FIN; f++) acc += sx[row * FIN + f] * sW[f * DD + lane];
                x1b[n * DD + lane] = f2b(fmaxf(acc, 0.f));
            }
        }
    } else {
        int tid = (blockIdx.x - 1563) * 256 + threadIdx.x;
        int stride = 1024 * 256;
        for (int idx = tid; idx < 65 * 4096; idx += stride) {
            int kc = idx >> 12;
            int rem = idx & 4095;
            int f = rem >> 9;
            int ln = (rem >> 3) & 63;
            int j = idx & 7;
            int s = f >> 2, c = f & 3;
            int o = c * 16 + (ln & 15);
            int r = kc * 64 + s * 32 + (ln >> 4) * 8 + j;
            float v = (r < 4096) ? We2[(r >> 6) * 4096 + (r & 63) * 64 + o]
                                 : be2[(r - 4096) * 64 + o];
            Bt2[idx] = f2b(v);
        }
        for (int idx = tid; idx < NN * DD; idx += stride) agg[idx] = 0.f;
        for (int idx = tid; idx < NG * DD; idx += stride) pooled[idx] = 0.f;
        if (use_csr) {
            const bool i64 = idx_is_i64(eidx);
            for (int idx = tid; idx < NE; idx += stride)
                atomicAdd(&cur[ld_dst(eidx, idx, i64)], 1);
        }
    }
}

// ---- exclusive scan of per-node counts -> off[], cur[] (single block) --------------------
__global__ __launch_bounds__(1024) void k_scan(int* __restrict__ cur, int* __restrict__ off) {
    __shared__ int part[1024];
    int tid = threadIdx.x;
    int base = tid * 25;
    int s = 0;
    for (int j = 0; j < 25; j++) {
        int i = base + j;
        if (i < NN) s += cur[i];
    }
    part[tid] = s;
    __syncthreads();
    for (int d = 1; d < 1024; d <<= 1) {
        int v = (tid >= d) ? part[tid - d] : 0;
        __syncthreads();
        part[tid] += v;
        __syncthreads();
    }
    int run = (tid > 0) ? part[tid - 1] : 0;
    for (int j = 0; j < 25; j++) {
        int i = base + j;
        if (i < NN) {
            int v = cur[i];
            off[i] = run;
            cur[i] = run;
            run += v;
        }
    }
    if (tid == 1023) off[NN] = part[1023];
}

// ---- fused NNConv message GEMM -----------------------------------------------------------
// v5: same pipelined K-loop as v4, but CSR mode replaces the 6.4M device-scope f32
// atomicAdds (round 0-3's invariant bottleneck: WRITE_SIZE == #atomics*4B -> per-atomic
// HBM write-through at ~76 Gop/s ceiling) with plain coalesced stores into a slot-ordered
// per-edge message buffer. Slot claim = 1 int atomic per edge.
template<bool CSR>
__global__ __launch_bounds__(512, 4) void k_msg(const float* __restrict__ ea,
                                                const int* __restrict__ eidx,
                                                const float* __restrict__ We1,
                                                const float* __restrict__ be1,
                                                const u16* __restrict__ x1b,
                                                const u16* __restrict__ Bt2,
                                                float* __restrict__ agg,
                                                int* __restrict__ cur,
                                                float* __restrict__ msgbuf) {
    __shared__ __align__(16) u16 sX[128 * 72];   // gathered x1 rows (bf16), pad 72
    __shared__ __align__(16) float sT[65 * 128]; // t transposed [k][e], f32; row 64 = 1.0
    __shared__ float sWe1[8 * 64];
    __shared__ float sbe1[64];
    __shared__ int sDst[128];                    // CSR: slot index; else: dst node
    const int tid = threadIdx.x;
    const int lane = tid & 63, wv = tid >> 6;
    const int ll = lane & 15, quad = lane >> 4;
    const int rh = wv >> 2, cq = wv & 3;       // row-half, col-quarter
    const int e0 = blockIdx.x * 128;
    const bool i64 = idx_is_i64(eidx);

    if (tid < 512) sWe1[tid] = We1[tid];
    if (tid < 64) sbe1[tid] = be1[tid];
    if (tid < 128) {
        int e = e0 + tid;
        if (CSR) {
            int s = 0;
            if (e < NE) s = atomicAdd(&cur[ld_dst(eidx, e, i64)], 1);
            sDst[tid] = s;
        } else {
            sDst[tid] = (e < NE) ? ld_dst(eidx, e, i64) : 0;
        }
        sT[64 * 128 + tid] = 1.0f;             // bias chunk: t = 1
    }

    // phase 1: gather x1 rows (bf16) for 128 edges; each thread: 32 B of one row
    const int el4 = tid >> 2, seg = tid & 3;
    const int eg4 = e0 + el4;
    {
        if (eg4 < NE) {
            int sv = ld_src(eidx, eg4, i64);
            const u16* xr = x1b + sv * 64 + seg * 16;
            *(uint4*)&sX[el4 * 72 + seg * 16]     = *(const uint4*)(xr);
            *(uint4*)&sX[el4 * 72 + seg * 16 + 8] = *(const uint4*)(xr + 8);
        } else {
            uint4 z = make_uint4(0, 0, 0, 0);
            *(uint4*)&sX[el4 * 72 + seg * 16]     = z;
            *(uint4*)&sX[el4 * 72 + seg * 16 + 8] = z;
        }
    }
    float eav[8];
    if (eg4 < NE) {
        f32x4 v0 = *(const f32x4*)(ea + eg4 * 8);
        f32x4 v1 = *(const f32x4*)(ea + eg4 * 8 + 4);
        #pragma unroll
        for (int f = 0; f < 4; f++) { eav[f] = v0[f]; eav[4 + f] = v1[f]; }
    } else {
        #pragma unroll
        for (int f = 0; f < 8; f++) eav[f] = 0.f;
    }
    __syncthreads();

    // phase 2: t[e,k] = relu(ea @ We1 + be1); each thread: 16 k-values of its edge (f32)
    {
        int k0 = seg * 16;
        for (int kk = 0; kk < 16; kk++) {
            int k = k0 + kk;
            float acc = sbe1[k];
            #pragma unroll
            for (int f = 0; f < 8; f++) acc += eav[f] * sWe1[f * 64 + k];
            sT[k * 128 + el4] = (eg4 < NE) ? fmaxf(acc, 0.f) : 0.f;
        }
    }
    __syncthreads();   // last barrier — K-loop below is barrier-free

    // fixed A-fragments: this wave's 4 row-tiles (rows rh*64 .. rh*64+63)
    short8 xa[4][2];
    #pragma unroll
    for (int rt = 0; rt < 4; rt++)
        #pragma unroll
        for (int s = 0; s < 2; s++)
            xa[rt][s] = *(const short8*)&sX[(rh * 64 + rt * 16 + ll) * 72 + s * 32 + quad * 8];

    f32x4 msg[4];
    #pragma unroll
    for (int rt = 0; rt < 4; rt++) msg[rt] = (f32x4){0.f, 0.f, 0.f, 0.f};

    // coalesced per-lane B pointers for this wave's column quarter
    const u16* gB0 = Bt2 + (0 * 4 + cq) * 512 + lane * 8;
    const u16* gB1 = Bt2 + (1 * 4 + cq) * 512 + lane * 8;
    const f32x4 zero = (f32x4){0.f, 0.f, 0.f, 0.f};
    const int tkoff = rh * 64 + quad * 4;

    // pipeline prologue: B for kc 0,1 in flight; tk for kc 0 in regs
    short8 c00 = *(const short8*)(gB0);
    short8 c01 = *(const short8*)(gB1);
    short8 c10 = *(const short8*)(gB0 + 4096);
    short8 c11 = *(const short8*)(gB1 + 4096);
    f32x4 tkA[4], tkB[4];
    #pragma unroll
    for (int rt = 0; rt < 4; rt++)
        tkA[rt] = *(const f32x4*)&sT[tkoff + rt * 16];

    for (int kc = 0; kc < 62; kc += 2) {
        // prefetch B two kc ahead
        short8 n00 = *(const short8*)(gB0 + (kc + 2) * 4096);
        short8 n01 = *(const short8*)(gB1 + (kc + 2) * 4096);
        short8 n10 = *(const short8*)(gB0 + (kc + 3) * 4096);
        short8 n11 = *(const short8*)(gB1 + (kc + 3) * 4096);
        // prefetch tk one kc ahead
        #pragma unroll
        for (int rt = 0; rt < 4; rt++)
            tkB[rt] = *(const f32x4*)&sT[(kc + 1) * 128 + tkoff + rt * 16];
        // compute kc (independent q0,q1)
        #pragma unroll
        for (int rt = 0; rt < 4; rt++) {
            f32x4 q0 = __builtin_amdgcn_mfma_f32_16x16x32_bf16(xa[rt][0], c00, zero, 0, 0, 0);
            f32x4 q1 = __builtin_amdgcn_mfma_f32_16x16x32_bf16(xa[rt][1], c01, zero, 0, 0, 0);
            msg[rt] += tkA[rt] * q0;
            msg[rt] += tkA[rt] * q1;
        }
        #pragma unroll
        for (int rt = 0; rt < 4; rt++)
            tkA[rt] = *(const f32x4*)&sT[(kc + 2) * 128 + tkoff + rt * 16];
        // compute kc+1
        #pragma unroll
        for (int rt = 0; rt < 4; rt++) {
            f32x4 q0 = __builtin_amdgcn_mfma_f32_16x16x32_bf16(xa[rt][0], c10, zero, 0, 0, 0);
            f32x4 q1 = __builtin_amdgcn_mfma_f32_16x16x32_bf16(xa[rt][1], c11, zero, 0, 0, 0);
            msg[rt] += tkB[rt] * q0;
            msg[rt] += tkB[rt] * q1;
        }
        c00 = n00; c01 = n01; c10 = n10; c11 = n11;
    }
    // tail: kc = 62, 63 (in c*), then bias chunk 64 (prefetched into n0*)
    {
        short8 n00 = *(const short8*)(gB0 + 64 * 4096);
        short8 n01 = *(const short8*)(gB1 + 64 * 4096);
        #pragma unroll
        for (int rt = 0; rt < 4; rt++)
            tkB[rt] = *(const f32x4*)&sT[63 * 128 + tkoff + rt * 16];
        #pragma unroll
        for (int rt = 0; rt < 4; rt++) {
            f32x4 q0 = __builtin_amdgcn_mfma_f32_16x16x32_bf16(xa[rt][0], c00, zero, 0, 0, 0);
            f32x4 q1 = __builtin_amdgcn_mfma_f32_16x16x32_bf16(xa[rt][1], c01, zero, 0, 0, 0);
            msg[rt] += tkA[rt] * q0;
            msg[rt] += tkA[rt] * q1;
        }
        #pragma unroll
        for (int rt = 0; rt < 4; rt++)
            tkA[rt] = *(const f32x4*)&sT[64 * 128 + tkoff + rt * 16];  // = 1.0
        #pragma unroll
        for (int rt = 0; rt < 4; rt++) {
            f32x4 q0 = __builtin_amdgcn_mfma_f32_16x16x32_bf16(xa[rt][0], c10, zero, 0, 0, 0);
            f32x4 q1 = __builtin_amdgcn_mfma_f32_16x16x32_bf16(xa[rt][1], c11, zero, 0, 0, 0);
            msg[rt] += tkB[rt] * q0;
            msg[rt] += tkB[rt] * q1;
        }
        #pragma unroll
        for (int rt = 0; rt < 4; rt++) {
            f32x4 q0 = __builtin_amdgcn_mfma_f32_16x16x32_bf16(xa[rt][0], n00, zero, 0, 0, 0);
            f32x4 q1 = __builtin_amdgcn_mfma_f32_16x16x32_bf16(xa[rt][1], n01, zero, 0, 0, 0);
            msg[rt] += tkA[rt] * q0;
            msg[rt] += tkA[rt] * q1;
        }
    }

    // epilogue: row = rh*64 + rt*16 + quad*4 + r, col = cq*16 + ll
    #pragma unroll
    for (int rt = 0; rt < 4; rt++) {
        #pragma unroll
        for (int r = 0; r < 4; r++) {
            int el = rh * 64 + rt * 16 + quad * 4 + r;
            int eg = e0 + el;
            if (eg < NE) {
                int d = sDst[el];
                if (CSR) msgbuf[d * 64 + cq * 16 + ll] = msg[rt][r];
                else     atomicAdd(&agg[d * 64 + cq * 16 + ll], msg[rt][r]);
            }
        }
    }
}

// ---- GRU via MFMA; CSR mode gathers per-node messages from slot-ordered msgbuf -----------
template<bool CSR>
__global__ __launch_bounds__(256) void k_gru(const u16* __restrict__ x1b,
                                             const float* __restrict__ agg,
                                             const int* __restrict__ off,
                                             const float* __restrict__ msgbuf,
                                             const float* __restrict__ Wroot,
                                             const float* __restrict__ bconv,
                                             const float* __restrict__ Wi,
                                             const float* __restrict__ Wh,
                                             const float* __restrict__ bi,
                                             const float* __restrict__ bh,
                                             const int* __restrict__ batch,
                                             float* __restrict__ pooled) {
    __shared__ __align__(16) u16 sWi[192 * 72];
    __shared__ __align__(16) u16 sWh[192 * 72];
    __shared__ __align__(16) u16 sX2[64 * 72];
    __shared__ int sBatch[64];
    const int tid = threadIdx.x;
    const int lane = tid & 63, wv = tid >> 6;
    const int ll = lane & 15, quad = lane >> 4;
    const int n0 = blockIdx.x * 64;

    for (int idx = tid; idx < 64 * 16; idx += 256) {
        int n = idx & 63, k4 = (idx >> 6) * 4;
        ushort4 a;
        a.x = f2b(Wroot[(k4 + 0) * 64 + n]);
        a.y = f2b(Wroot[(k4 + 1) * 64 + n]);
        a.z = f2b(Wroot[(k4 + 2) * 64 + n]);
        a.w = f2b(Wroot[(k4 + 3) * 64 + n]);
        *(ushort4*)&sWi[n * 72 + k4] = a;
    }
    if (tid < 64) {
        int n = n0 + tid;
        sBatch[tid] = (n < NN) ? batch[n] : -1;
    }
    __syncthreads();

    short8 ha[2];
    {
        int n = n0 + wv * 16 + ll;
        #pragma unroll
        for (int kc = 0; kc < 2; kc++) {
            if (n < NN) ha[kc] = *(const short8*)(x1b + n * 64 + kc * 32 + quad * 8);
            else        ha[kc] = (short8){0,0,0,0,0,0,0,0};
        }
    }
    f32x4 acc1[4];
    #pragma unroll
    for (int c = 0; c < 4; c++) acc1[c] = (f32x4){0.f, 0.f, 0.f, 0.f};
    #pragma unroll
    for (int kc = 0; kc < 2; kc++) {
        #pragma unroll
        for (int c = 0; c < 4; c++) {
            short8 b = *(const short8*)&sWi[(c * 16 + ll) * 72 + kc * 32 + quad * 8];
            acc1[c] = __builtin_amdgcn_mfma_f32_16x16x32_bf16(ha[kc], b, acc1[c], 0, 0, 0);
        }
    }

    // aggregation: CSR gather over this node's contiguous slot range, cols ll + {0,16,32,48}
    float aggv[4][4];
    #pragma unroll
    for (int r = 0; r < 4; r++)
        #pragma unroll
        for (int c = 0; c < 4; c++) aggv[r][c] = 0.f;
    if (CSR) {
        #pragma unroll
        for (int r = 0; r < 4; r++) {
            int row = wv * 16 + quad * 4 + r;
            int n = n0 + row;
            if (n < NN) {
                int s0 = off[n], s1 = off[n + 1];
                float a0 = 0.f, a1 = 0.f, a2 = 0.f, a3 = 0.f;
                for (int i = s0; i < s1; i++) {
                    const float* mr = msgbuf + i * 64 + ll;
                    a0 += mr[0]; a1 += mr[16]; a2 += mr[32]; a3 += mr[48];
                }
                aggv[r][0] = a0; aggv[r][1] = a1; aggv[r][2] = a2; aggv[r][3] = a3;
            }
        }
    }

    #pragma unroll
    for (int c = 0; c < 4; c++) {
        int col = c * 16 + ll;
        float bcv = bconv[col];
        #pragma unroll
        for (int r = 0; r < 4; r++) {
            int row = wv * 16 + quad * 4 + r;
            int n = n0 + row;
            float v = 0.f;
            if (n < NN) {
                float ag = CSR ? aggv[r][c] : agg[n * 64 + col];
                v = fmaxf(acc1[c][r] + ag + bcv, 0.f);
            }
            sX2[row * 72 + col] = f2b(v);
        }
    }
    __syncthreads();

    for (int idx = tid; idx < 192 * 16; idx += 256) {
        int j = idx >> 4, i4 = (idx & 15) * 4;
        float4 wi4 = *(const float4*)&Wi[j * 64 + i4];
        float4 wh4 = *(const float4*)&Wh[j * 64 + i4];
        ushort4 a, b;
        a.x = f2b(wi4.x); a.y = f2b(wi4.y); a.z = f2b(wi4.z); a.w = f2b(wi4.w);
        b.x = f2b(wh4.x); b.y = f2b(wh4.y); b.z = f2b(wh4.z); b.w = f2b(wh4.w);
        *(ushort4*)&sWi[j * 72 + i4] = a;
        *(ushort4*)&sWh[j * 72 + i4] = b;
    }
    __syncthreads();

    short8 xa[2];
    #pragma unroll
    for (int kc = 0; kc < 2; kc++)
        xa[kc] = *(const short8*)&sX2[(wv * 16 + ll) * 72 + kc * 32 + quad * 8];

    f32x4 agi[12], agh[12];
    #pragma unroll
    for (int c = 0; c < 12; c++) { agi[c] = (f32x4){0.f,0.f,0.f,0.f}; agh[c] = (f32x4){0.f,0.f,0.f,0.f}; }
    #pragma unroll
    for (int kc = 0; kc < 2; kc++) {
        #pragma unroll
        for (int c = 0; c < 12; c++) {
            short8 bi8 = *(const short8*)&sWi[(c * 16 + ll) * 72 + kc * 32 + quad * 8];
            short8 bh8 = *(const short8*)&sWh[(c * 16 + ll) * 72 + kc * 32 + quad * 8];
            agi[c] = __builtin_amdgcn_mfma_f32_16x16x32_bf16(xa[kc], bi8, agi[c], 0, 0, 0);
            agh[c] = __builtin_amdgcn_mfma_f32_16x16x32_bf16(ha[kc], bh8, agh[c], 0, 0, 0);
        }
    }

    float hnv[4][4];
    #pragma unroll
    for (int c0 = 0; c0 < 4; c0++) {
        int d = c0 * 16 + ll;
        float bir = bi[d],        bhr = bh[d];
        float biz = bi[64 + d],   bhz = bh[64 + d];
        float bin = bi[128 + d],  bhn = bh[128 + d];
        #pragma unroll
        for (int r = 0; r < 4; r++) {
            int row = wv * 16 + quad * 4 + r;
            int n = n0 + row;
            float gir = agi[c0][r] + bir,     ghr = agh[c0][r] + bhr;
            float giz = agi[c0 + 4][r] + biz, ghz = agh[c0 + 4][r] + bhz;
            float gin = agi[c0 + 8][r] + bin, ghn = agh[c0 + 8][r] + bhn;
            float rg = 1.f / (1.f + __expf(-(gir + ghr)));
            float zg = 1.f / (1.f + __expf(-(giz + ghz)));
            float ng = tanhf(gin + rg * ghn);
            float hv = (n < NN) ? b2f(x1b[n * 64 + d]) : 0.f;
            hnv[c0][r] = (n < NN) ? ((1.f - zg) * ng + zg * hv) : 0.f;
        }
    }
    __syncthreads();

    float* hbuf = (float*)sWi;
    #pragma unroll
    for (int c0 = 0; c0 < 4; c0++) {
        int d = c0 * 16 + ll;
        #pragma unroll
        for (int r = 0; r < 4; r++) {
            int row = wv * 16 + quad * 4 + r;
            hbuf[row * 65 + d] = hnv[c0][r];
        }
    }
    __syncthreads();

    {
        int d = lane;
        float sum = 0.f;
        int pb = sBatch[wv * 16];
        #pragma unroll
        for (int rr = 0; rr < 16; rr++) {
            int row = wv * 16 + rr;
            int b = sBatch[row];
            float v = hbuf[row * 65 + d];
            if (b != pb) {
                if (pb >= 0) atomicAdd(&pooled[pb * 64 + d], sum);
                sum = v; pb = b;
            } else {
                sum += v;
            }
        }
        if (pb >= 0) atomicAdd(&pooled[pb * 64 + d], sum);
    }
}

// ---- heads: two 3-layer MLPs over pooled; output FLOAT32 ---------------------------------
__global__ __launch_bounds__(256) void k_heads(const float* __restrict__ pooled,
                                               const float* __restrict__ W11, const float* __restrict__ b11,
                                               const float* __restrict__ W12, const float* __restrict__ b12,
                                               const float* __restrict__ W13, const float* __restrict__ b13,
                                               const float* __restrict__ W21, const float* __restrict__ b21,
                                               const float* __restrict__ W22, const float* __restrict__ b22,
                                               const float* __restrict__ W23, const float* __restrict__ b23,
                                               float* __restrict__ out) {
    __shared__ float sV[4][64];
    __shared__ float sA[4][64];
    int tid = threadIdx.x, lane = tid & 63, wv = tid >> 6;
    int g = blockIdx.x * 4 + wv;
    if (g >= NG) return;
    float p = pooled[g * 64 + lane];
    sV[wv][lane] = p;
    float y[2];
    const float* W1s[2] = {W11, W21}; const float* b1s[2] = {b11, b21};
    const float* W2s[2] = {W12, W22}; const float* b2s[2] = {b12, b22};
    const float* W3s[2] = {W13, W23}; const float* b3s[2] = {b13, b23};
    #pragma unroll
    for (int hd = 0; hd < 2; hd++) {
        float a = b1s[hd][lane];
        #pragma unroll 8
        for (int i = 0; i < 64; i++) a += sV[wv][i] * W1s[hd][i * 64 + lane];
        a = fmaxf(a, 0.f);
        sA[wv][lane] = a;
        float a2 = b2s[hd][lane];
        #pragma unroll 8
        for (int i = 0; i < 64; i++) a2 += sA[wv][i] * W2s[hd][i * 64 + lane];
        a2 = fmaxf(a2, 0.f);
        float part = a2 * W3s[hd][lane];
        #pragma unroll
        for (int m = 32; m > 0; m >>= 1) part += __shfl_xor(part, m, 64);
        y[hd] = part + b3s[hd][0];
    }
    if (lane == 0) {
        out[g * 2 + 0] = y[0];
        out[g * 2 + 1] = y[1];
    }
}

extern "C" void kernel_launch(void* const* d_in, const int* in_sizes, int n_in,
                              void* d_out, int out_size, void* d_ws, size_t ws_size,
                              hipStream_t stream) {
    const float* x     = (const float*)d_in[0];
    const int* eidx    = (const int*)d_in[1];
    const float* ea    = (const float*)d_in[2];
    const int* batch   = (const int*)d_in[3];
    const float* W0    = (const float*)d_in[4];  const float* b0    = (const float*)d_in[5];
    const float* We1   = (const float*)d_in[6];  const float* be1   = (const float*)d_in[7];
    const float* We2   = (const float*)d_in[8];  const float* be2   = (const float*)d_in[9];
    const float* Wroot = (const float*)d_in[10]; const float* bconv = (const float*)d_in[11];
    const float* Wi    = (const float*)d_in[12]; const float* Wh    = (const float*)d_in[13];
    const float* bi    = (const float*)d_in[14]; const float* bh    = (const float*)d_in[15];
    const float* W11   = (const float*)d_in[16]; const float* b11   = (const float*)d_in[17];
    const float* W12   = (const float*)d_in[18]; const float* b12   = (const float*)d_in[19];
    const float* W13   = (const float*)d_in[20]; const float* b13   = (const float*)d_in[21];
    const float* W21   = (const float*)d_in[22]; const float* b21   = (const float*)d_in[23];
    const float* W22   = (const float*)d_in[24]; const float* b22   = (const float*)d_in[25];
    const float* W23   = (const float*)d_in[26]; const float* b23   = (const float*)d_in[27];
    float* out = (float*)d_out;

    // workspace layout (CSR path needs 36,188,544 B; head fits old 10.39 MB footprint)
    char* ws = (char*)d_ws;
    float* agg    = (float*)(ws);                       // 6,400,000 B (fallback path)
    u16*   x1b    = (u16*)(ws + 6400000);               // 3,200,000 B
    u16*   Bt2    = (u16*)(ws + 9600000);               //   532,480 B
    float* pooled = (float*)(ws + 10132480);            //   256,000 B
    int*   off    = (int*)(ws + 10388480);              //   100,032 B
    int*   cur    = (int*)(ws + 10488512);              //   100,032 B
    float* msgbuf = (float*)(ws + 10588544);            // 25,600,000 B
    const size_t NEED_CSR = 36188544;
    const int use_csr = (ws_size >= NEED_CSR) ? 1 : 0;

    if (use_csr) {
        hipMemsetAsync(cur, 0, NN * sizeof(int), stream);
        hipLaunchKernelGGL(k_pre, dim3(2587), dim3(256), 0, stream,
                           x, W0, b0, x1b, We2, be2, agg, pooled, Bt2, eidx, cur, 1);
        hipLaunchKernelGGL(k_scan, dim3(1), dim3(1024), 0, stream, cur, off);
        hipLaunchKernelGGL((k_msg<true>), dim3(782), dim3(512), 0, stream,
                           ea, eidx, We1, be1, x1b, Bt2, agg, cur, msgbuf);
        hipLaunchKernelGGL((k_gru<true>), dim3(391), dim3(256), 0, stream,
                           x1b, agg, off, msgbuf, Wroot, bconv, Wi, Wh, bi, bh, batch, pooled);
    } else {
        hipLaunchKernelGGL(k_pre, dim3(2587), dim3(256), 0, stream,
                           x, W0, b0, x1b, We2, be2, agg, pooled, Bt2, eidx, cur, 0);
        hipLaunchKernelGGL((k_msg<false>), dim3(782), dim3(512), 0, stream,
                           ea, eidx, We1, be1, x1b, Bt2, agg, cur, msgbuf);
        hipLaunchKernelGGL((k_gru<false>), dim3(391), dim3(256), 0, stream,
                           x1b, agg, off, msgbuf, Wroot, bconv, Wi, Wh, bi, bh, batch, pooled);
    }
    hipLaunchKernelGGL(k_heads, dim3(250), dim3(256), 0, stream, pooled,
                       W11, b11, W12, b12, W13, b13, W21, b21, W22, b22, W23, b23, out);
}

// Round 5
// 248.810 us; speedup vs baseline: 1.2191x; 1.2191x over previous
//
#include <hip/hip_runtime.h>
#include <hip/hip_bf16.h>

#define NN 25000
#define NE 100000
#define FIN 32
#define DD 64
#define NG 1000

typedef unsigned short u16;
typedef __attribute__((ext_vector_type(8))) short short8;
typedef __attribute__((ext_vector_type(4))) float f32x4;

__device__ __forceinline__ float b2f(u16 u) {
    union { unsigned int i; float f; } v; v.i = ((unsigned int)u) << 16; return v.f;
}
__device__ __forceinline__ u16 f2b(float f) {
    __hip_bfloat16 h = __float2bfloat16(f);
    return __builtin_bit_cast(u16, h);
}
// edge_index may be int64 read as int32 words: odd words would all be 0.
__device__ __forceinline__ bool idx_is_i64(const int* e) {
    return (e[1] == 0) & (e[3] == 0) & (e[5] == 0) & (e[7] == 0) & (e[9] == 0);
}
__device__ __forceinline__ int ld_src(const int* e, int i, bool i64) {
    return i64 ? e[2 * i] : e[i];
}
__device__ __forceinline__ int ld_dst(const int* e, int i, bool i64) {
    return i64 ? e[2 * (NE + i)] : e[NE + i];
}

// ---- fused pre-pass: blocks [0,1563) = lin0 (16 rows/block); [1563,2587) = Bt2 + zero ----
// Bt2 fragment-major: idx = kc*4096 + (s*4+c)*512 + lane*8 + j  holds
// B[k = kc*64 + s*32 + (lane>>4)*8 + j][o = c*16 + (lane&15)]  (r>=4096 -> be2 rows).
__global__ __launch_bounds__(256) void k_pre(const float* __restrict__ x,
                                             const float* __restrict__ W0,
                                             const float* __restrict__ b0,
                                             u16* __restrict__ x1b,
                                             const float* __restrict__ We2,
                                             const float* __restrict__ be2,
                                             float* __restrict__ agg,
                                             float* __restrict__ pooled,
                                             u16* __restrict__ Bt2) {
    __shared__ float sW[FIN * DD];
    __shared__ float sx[16 * FIN];
    if (blockIdx.x < 1563) {
        int tid = threadIdx.x;
        for (int i = tid; i < FIN * DD; i += 256) sW[i] = W0[i];
        int nbase = blockIdx.x * 16;
        for (int i = tid; i < 16 * FIN; i += 256) {
            int nl = i >> 5, f = i & 31;
            int n = nbase + nl;
            sx[i] = (n < NN) ? x[n * FIN + f] : 0.f;
        }
        __syncthreads();
        int lane = tid & 63, nl = tid >> 6;
        float bias = b0[lane];
        #pragma unroll
        for (int rr = 0; rr < 4; rr++) {
            int row = nl * 4 + rr;
            int n = nbase + row;
            if (n < NN) {
                float acc = bias;
                #pragma unroll
                for (int f = 0; f < FIN; f++) acc += sx[row * FIN + f] * sW[f * DD + lane];
                x1b[n * DD + lane] = f2b(fmaxf(acc, 0.f));
            }
        }
    } else {
        int tid = (blockIdx.x - 1563) * 256 + threadIdx.x;
        int stride = 1024 * 256;
        for (int idx = tid; idx < 65 * 4096; idx += stride) {
            int kc = idx >> 12;
            int rem = idx & 4095;
            int f = rem >> 9;
            int ln = (rem >> 3) & 63;
            int j = idx & 7;
            int s = f >> 2, c = f & 3;
            int o = c * 16 + (ln & 15);
            int r = kc * 64 + s * 32 + (ln >> 4) * 8 + j;
            float v = (r < 4096) ? We2[(r >> 6) * 4096 + (r & 63) * 64 + o]
                                 : be2[(r - 4096) * 64 + o];
            Bt2[idx] = f2b(v);
        }
        for (int idx = tid; idx < NN * DD; idx += stride) agg[idx] = 0.f;
        for (int idx = tid; idx < NG * DD; idx += stride) pooled[idx] = 0.f;
    }
}

// ---- fused NNConv message GEMM + scatter -------------------------------------------------
// v6 "register diet for occupancy": all rounds 0-4 ran at 16 waves/CU (128 regs/wave cap)
// with every pipe <31% busy -> latency-bound, needs TLP. Diet: no sX (A-frags direct from
// global x1b), single tk buffer, B prefetch depth-1, uniform 65-chunk loop. Live state
// ~88 regs; __launch_bounds__(512,6) caps ~85 -> 3 blocks/CU = 24 waves (LDS 36.6KB -> ok).
__global__ __launch_bounds__(512, 6) void k_msg(const float* __restrict__ ea,
                                                const int* __restrict__ eidx,
                                                const float* __restrict__ We1,
                                                const float* __restrict__ be1,
                                                const u16* __restrict__ x1b,
                                                const u16* __restrict__ Bt2,
                                                float* __restrict__ agg) {
    __shared__ __align__(16) float sT[65 * 128]; // t transposed [k][e], f32; row 64 = 1.0
    __shared__ float sWe1[8 * 64];
    __shared__ float sbe1[64];
    __shared__ int sDst[128];
    __shared__ int sSrc[128];
    const int tid = threadIdx.x;
    const int lane = tid & 63, wv = tid >> 6;
    const int ll = lane & 15, quad = lane >> 4;
    const int rh = wv >> 2, cq = wv & 3;       // row-half, col-quarter
    const int e0 = blockIdx.x * 128;
    const bool i64 = idx_is_i64(eidx);

    sWe1[tid & 511] = We1[tid & 511];
    if (tid < 64) sbe1[tid] = be1[tid];
    if (tid < 128) {
        int e = e0 + tid;
        sDst[tid] = (e < NE) ? ld_dst(eidx, e, i64) : 0;
        sSrc[tid] = (e < NE) ? ld_src(eidx, e, i64) : 0;
        sT[64 * 128 + tid] = 1.0f;             // bias chunk: t = 1
    }

    // per-thread edge-attr load (edge el4 = tid>>2; seg = tid&3 -> 16 k's in phase 2)
    const int el4 = tid >> 2, seg = tid & 3;
    const int eg4 = e0 + el4;
    float eav[8];
    if (eg4 < NE) {
        f32x4 v0 = *(const f32x4*)(ea + eg4 * 8);
        f32x4 v1 = *(const f32x4*)(ea + eg4 * 8 + 4);
        #pragma unroll
        for (int f = 0; f < 4; f++) { eav[f] = v0[f]; eav[4 + f] = v1[f]; }
    } else {
        #pragma unroll
        for (int f = 0; f < 8; f++) eav[f] = 0.f;
    }
    __syncthreads();

    // phase 2: t[e,k] = relu(ea @ We1 + be1); each thread: 16 k-values of its edge (f32)
    {
        int k0 = seg * 16;
        for (int kk = 0; kk < 16; kk++) {
            int k = k0 + kk;
            float acc = sbe1[k];
            #pragma unroll
            for (int f = 0; f < 8; f++) acc += eav[f] * sWe1[f * 64 + k];
            sT[k * 128 + el4] = (eg4 < NE) ? fmaxf(acc, 0.f) : 0.f;
        }
    }
    __syncthreads();   // last barrier — K-loop below is barrier-free

    // fixed A-fragments: this wave's 4 row-tiles, loaded DIRECT from global x1b
    short8 xa[4][2];
    #pragma unroll
    for (int rt = 0; rt < 4; rt++) {
        int sv = sSrc[rh * 64 + rt * 16 + ll];
        const u16* xr = x1b + sv * 64 + quad * 8;
        xa[rt][0] = *(const short8*)(xr);
        xa[rt][1] = *(const short8*)(xr + 32);
    }

    f32x4 msg[4];
    #pragma unroll
    for (int rt = 0; rt < 4; rt++) msg[rt] = (f32x4){0.f, 0.f, 0.f, 0.f};

    // coalesced per-lane B pointers for this wave's column quarter
    const u16* gB0 = Bt2 + (0 * 4 + cq) * 512 + lane * 8;
    const u16* gB1 = Bt2 + (1 * 4 + cq) * 512 + lane * 8;
    const f32x4 zero = (f32x4){0.f, 0.f, 0.f, 0.f};
    const int tkoff = rh * 64 + quad * 4;

    // depth-1 B prefetch; uniform loop over all 65 chunks (row 64 of sT is the 1.0 bias row)
    short8 c0 = *(const short8*)(gB0);
    short8 c1 = *(const short8*)(gB1);

    for (int kc = 0; kc < 65; kc++) {
        int kn = (kc < 64) ? kc + 1 : 64;
        short8 n0 = *(const short8*)(gB0 + kn * 4096);
        short8 n1 = *(const short8*)(gB1 + kn * 4096);
        f32x4 tk[4];
        #pragma unroll
        for (int rt = 0; rt < 4; rt++)
            tk[rt] = *(const f32x4*)&sT[kc * 128 + tkoff + rt * 16];
        #pragma unroll
        for (int rt = 0; rt < 4; rt++) {
            f32x4 q0 = __builtin_amdgcn_mfma_f32_16x16x32_bf16(xa[rt][0], c0, zero, 0, 0, 0);
            f32x4 q1 = __builtin_amdgcn_mfma_f32_16x16x32_bf16(xa[rt][1], c1, zero, 0, 0, 0);
            msg[rt] += tk[rt] * q0;
            msg[rt] += tk[rt] * q1;
        }
        c0 = n0; c1 = n1;
    }

    // epilogue: row = rh*64 + rt*16 + quad*4 + r, col = cq*16 + ll; scatter into agg[dst]
    #pragma unroll
    for (int rt = 0; rt < 4; rt++) {
        #pragma unroll
        for (int r = 0; r < 4; r++) {
            int el = rh * 64 + rt * 16 + quad * 4 + r;
            int eg = e0 + el;
            if (eg < NE) {
                int d = sDst[el];
                atomicAdd(&agg[d * 64 + cq * 16 + ll], msg[rt][r]);
            }
        }
    }
}

// ---- GRU via MFMA (round-3 verified) -----------------------------------------------------
__global__ __launch_bounds__(256) void k_gru(const u16* __restrict__ x1b,
                                             const float* __restrict__ agg,
                                             const float* __restrict__ Wroot,
                                             const float* __restrict__ bconv,
                                             const float* __restrict__ Wi,
                                             const float* __restrict__ Wh,
                                             const float* __restrict__ bi,
                                             const float* __restrict__ bh,
                                             const int* __restrict__ batch,
                                             float* __restrict__ pooled) {
    __shared__ __align__(16) u16 sWi[192 * 72];
    __shared__ __align__(16) u16 sWh[192 * 72];
    __shared__ __align__(16) u16 sX2[64 * 72];
    __shared__ int sBatch[64];
    const int tid = threadIdx.x;
    const int lane = tid & 63, wv = tid >> 6;
    const int ll = lane & 15, quad = lane >> 4;
    const int n0 = blockIdx.x * 64;

    for (int idx = tid; idx < 64 * 16; idx += 256) {
        int n = idx & 63, k4 = (idx >> 6) * 4;
        ushort4 a;
        a.x = f2b(Wroot[(k4 + 0) * 64 + n]);
        a.y = f2b(Wroot[(k4 + 1) * 64 + n]);
        a.z = f2b(Wroot[(k4 + 2) * 64 + n]);
        a.w = f2b(Wroot[(k4 + 3) * 64 + n]);
        *(ushort4*)&sWi[n * 72 + k4] = a;
    }
    if (tid < 64) {
        int n = n0 + tid;
        sBatch[tid] = (n < NN) ? batch[n] : -1;
    }
    __syncthreads();

    short8 ha[2];
    {
        int n = n0 + wv * 16 + ll;
        #pragma unroll
        for (int kc = 0; kc < 2; kc++) {
            if (n < NN) ha[kc] = *(const short8*)(x1b + n * 64 + kc * 32 + quad * 8);
            else        ha[kc] = (short8){0,0,0,0,0,0,0,0};
        }
    }
    f32x4 acc1[4];
    #pragma unroll
    for (int c = 0; c < 4; c++) acc1[c] = (f32x4){0.f, 0.f, 0.f, 0.f};
    #pragma unroll
    for (int kc = 0; kc < 2; kc++) {
        #pragma unroll
        for (int c = 0; c < 4; c++) {
            short8 b = *(const short8*)&sWi[(c * 16 + ll) * 72 + kc * 32 + quad * 8];
            acc1[c] = __builtin_amdgcn_mfma_f32_16x16x32_bf16(ha[kc], b, acc1[c], 0, 0, 0);
        }
    }
    #pragma unroll
    for (int c = 0; c < 4; c++) {
        int col = c * 16 + ll;
        float bcv = bconv[col];
        #pragma unroll
        for (int r = 0; r < 4; r++) {
            int row = wv * 16 + quad * 4 + r;
            int n = n0 + row;
            float v = 0.f;
            if (n < NN) v = fmaxf(acc1[c][r] + agg[n * 64 + col] + bcv, 0.f);
            sX2[row * 72 + col] = f2b(v);
        }
    }
    __syncthreads();

    for (int idx = tid; idx < 192 * 16; idx += 256) {
        int j = idx >> 4, i4 = (idx & 15) * 4;
        float4 wi4 = *(const float4*)&Wi[j * 64 + i4];
        float4 wh4 = *(const float4*)&Wh[j * 64 + i4];
        ushort4 a, b;
        a.x = f2b(wi4.x); a.y = f2b(wi4.y); a.z = f2b(wi4.z); a.w = f2b(wi4.w);
        b.x = f2b(wh4.x); b.y = f2b(wh4.y); b.z = f2b(wh4.z); b.w = f2b(wh4.w);
        *(ushort4*)&sWi[j * 72 + i4] = a;
        *(ushort4*)&sWh[j * 72 + i4] = b;
    }
    __syncthreads();

    short8 xa[2];
    #pragma unroll
    for (int kc = 0; kc < 2; kc++)
        xa[kc] = *(const short8*)&sX2[(wv * 16 + ll) * 72 + kc * 32 + quad * 8];

    f32x4 agi[12], agh[12];
    #pragma unroll
    for (int c = 0; c < 12; c++) { agi[c] = (f32x4){0.f,0.f,0.f,0.f}; agh[c] = (f32x4){0.f,0.f,0.f,0.f}; }
    #pragma unroll
    for (int kc = 0; kc < 2; kc++) {
        #pragma unroll
        for (int c = 0; c < 12; c++) {
            short8 bi8 = *(const short8*)&sWi[(c * 16 + ll) * 72 + kc * 32 + quad * 8];
            short8 bh8 = *(const short8*)&sWh[(c * 16 + ll) * 72 + kc * 32 + quad * 8];
            agi[c] = __builtin_amdgcn_mfma_f32_16x16x32_bf16(xa[kc], bi8, agi[c], 0, 0, 0);
            agh[c] = __builtin_amdgcn_mfma_f32_16x16x32_bf16(ha[kc], bh8, agh[c], 0, 0, 0);
        }
    }

    float hnv[4][4];
    #pragma unroll
    for (int c0 = 0; c0 < 4; c0++) {
        int d = c0 * 16 + ll;
        float bir = bi[d],        bhr = bh[d];
        float biz = bi[64 + d],   bhz = bh[64 + d];
        float bin = bi[128 + d],  bhn = bh[128 + d];
        #pragma unroll
        for (int r = 0; r < 4; r++) {
            int row = wv * 16 + quad * 4 + r;
            int n = n0 + row;
            float gir = agi[c0][r] + bir,     ghr = agh[c0][r] + bhr;
            float giz = agi[c0 + 4][r] + biz, ghz = agh[c0 + 4][r] + bhz;
            float gin = agi[c0 + 8][r] + bin, ghn = agh[c0 + 8][r] + bhn;
            float rg = 1.f / (1.f + __expf(-(gir + ghr)));
            float zg = 1.f / (1.f + __expf(-(giz + ghz)));
            float ng = tanhf(gin + rg * ghn);
            float hv = (n < NN) ? b2f(x1b[n * 64 + d]) : 0.f;
            hnv[c0][r] = (n < NN) ? ((1.f - zg) * ng + zg * hv) : 0.f;
        }
    }
    __syncthreads();

    float* hbuf = (float*)sWi;
    #pragma unroll
    for (int c0 = 0; c0 < 4; c0++) {
        int d = c0 * 16 + ll;
        #pragma unroll
        for (int r = 0; r < 4; r++) {
            int row = wv * 16 + quad * 4 + r;
            hbuf[row * 65 + d] = hnv[c0][r];
        }
    }
    __syncthreads();

    {
        int d = lane;
        float sum = 0.f;
        int pb = sBatch[wv * 16];
        #pragma unroll
        for (int rr = 0; rr < 16; rr++) {
            int row = wv * 16 + rr;
            int b = sBatch[row];
            float v = hbuf[row * 65 + d];
            if (b != pb) {
                if (pb >= 0) atomicAdd(&pooled[pb * 64 + d], sum);
                sum = v; pb = b;
            } else {
                sum += v;
            }
        }
        if (pb >= 0) atomicAdd(&pooled[pb * 64 + d], sum);
    }
}

// ---- heads: two 3-layer MLPs over pooled; output FLOAT32 ---------------------------------
__global__ __launch_bounds__(256) void k_heads(const float* __restrict__ pooled,
                                               const float* __restrict__ W11, const float* __restrict__ b11,
                                               const float* __restrict__ W12, const float* __restrict__ b12,
                                               const float* __restrict__ W13, const float* __restrict__ b13,
                                               const float* __restrict__ W21, const float* __restrict__ b21,
                                               const float* __restrict__ W22, const float* __restrict__ b22,
                                               const float* __restrict__ W23, const float* __restrict__ b23,
                                               float* __restrict__ out) {
    __shared__ float sV[4][64];
    __shared__ float sA[4][64];
    int tid = threadIdx.x, lane = tid & 63, wv = tid >> 6;
    int g = blockIdx.x * 4 + wv;
    if (g >= NG) return;
    float p = pooled[g * 64 + lane];
    sV[wv][lane] = p;
    float y[2];
    const float* W1s[2] = {W11, W21}; const float* b1s[2] = {b11, b21};
    const float* W2s[2] = {W12, W22}; const float* b2s[2] = {b12, b22};
    const float* W3s[2] = {W13, W23}; const float* b3s[2] = {b13, b23};
    #pragma unroll
    for (int hd = 0; hd < 2; hd++) {
        float a = b1s[hd][lane];
        #pragma unroll 8
        for (int i = 0; i < 64; i++) a += sV[wv][i] * W1s[hd][i * 64 + lane];
        a = fmaxf(a, 0.f);
        sA[wv][lane] = a;
        float a2 = b2s[hd][lane];
        #pragma unroll 8
        for (int i = 0; i < 64; i++) a2 += sA[wv][i] * W2s[hd][i * 64 + lane];
        a2 = fmaxf(a2, 0.f);
        float part = a2 * W3s[hd][lane];
        #pragma unroll
        for (int m = 32; m > 0; m >>= 1) part += __shfl_xor(part, m, 64);
        y[hd] = part + b3s[hd][0];
    }
    if (lane == 0) {
        out[g * 2 + 0] = y[0];
        out[g * 2 + 1] = y[1];
    }
}

extern "C" void kernel_launch(void* const* d_in, const int* in_sizes, int n_in,
                              void* d_out, int out_size, void* d_ws, size_t ws_size,
                              hipStream_t stream) {
    const float* x     = (const float*)d_in[0];
    const int* eidx    = (const int*)d_in[1];
    const float* ea    = (const float*)d_in[2];
    const int* batch   = (const int*)d_in[3];
    const float* W0    = (const float*)d_in[4];  const float* b0    = (const float*)d_in[5];
    const float* We1   = (const float*)d_in[6];  const float* be1   = (const float*)d_in[7];
    const float* We2   = (const float*)d_in[8];  const float* be2   = (const float*)d_in[9];
    const float* Wroot = (const float*)d_in[10]; const float* bconv = (const float*)d_in[11];
    const float* Wi    = (const float*)d_in[12]; const float* Wh    = (const float*)d_in[13];
    const float* bi    = (const float*)d_in[14]; const float* bh    = (const float*)d_in[15];
    const float* W11   = (const float*)d_in[16]; const float* b11   = (const float*)d_in[17];
    const float* W12   = (const float*)d_in[18]; const float* b12   = (const float*)d_in[19];
    const float* W13   = (const float*)d_in[20]; const float* b13   = (const float*)d_in[21];
    const float* W21   = (const float*)d_in[22]; const float* b21   = (const float*)d_in[23];
    const float* W22   = (const float*)d_in[24]; const float* b22   = (const float*)d_in[25];
    const float* W23   = (const float*)d_in[26]; const float* b23   = (const float*)d_in[27];
    float* out = (float*)d_out;

    // workspace: total 10,388,480 B
    char* ws = (char*)d_ws;
    float* agg    = (float*)(ws);                       // 6,400,000 B
    u16*   x1b    = (u16*)(ws + 6400000);               // 3,200,000 B
    u16*   Bt2    = (u16*)(ws + 9600000);               //   532,480 B
    float* pooled = (float*)(ws + 10132480);            //   256,000 B

    hipLaunchKernelGGL(k_pre, dim3(2587), dim3(256), 0, stream,
                       x, W0, b0, x1b, We2, be2, agg, pooled, Bt2);
    hipLaunchKernelGGL(k_msg, dim3(782), dim3(512), 0, stream, ea, eidx, We1, be1, x1b, Bt2, agg);
    hipLaunchKernelGGL(k_gru, dim3(391), dim3(256), 0, stream, x1b, agg, Wroot, bconv,
                       Wi, Wh, bi, bh, batch, pooled);
    hipLaunchKernelGGL(k_heads, dim3(250), dim3(256), 0, stream, pooled,
                       W11, b11, W12, b12, W13, b13, W21, b21, W22, b22, W23, b23, out);
}

// Round 6
// 233.372 us; speedup vs baseline: 1.2998x; 1.0662x over previous
//
#include <hip/hip_runtime.h>
#include <hip/hip_bf16.h>

#define NN 25000
#define NE 100000
#define FIN 32
#define DD 64
#define NG 1000

typedef unsigned short u16;
typedef __attribute__((ext_vector_type(8))) short short8;
typedef __attribute__((ext_vector_type(4))) float f32x4;

__device__ __forceinline__ float b2f(u16 u) {
    union { unsigned int i; float f; } v; v.i = ((unsigned int)u) << 16; return v.f;
}
__device__ __forceinline__ u16 f2b(float f) {
    __hip_bfloat16 h = __float2bfloat16(f);
    return __builtin_bit_cast(u16, h);
}
// edge_index may be int64 read as int32 words: odd words would all be 0.
__device__ __forceinline__ bool idx_is_i64(const int* e) {
    return (e[1] == 0) & (e[3] == 0) & (e[5] == 0) & (e[7] == 0) & (e[9] == 0);
}
__device__ __forceinline__ int ld_src(const int* e, int i, bool i64) {
    return i64 ? e[2 * i] : e[i];
}
__device__ __forceinline__ int ld_dst(const int* e, int i, bool i64) {
    return i64 ? e[2 * (NE + i)] : e[NE + i];
}

// ---- fused pre-pass ----------------------------------------------------------------------
// blocks [0,1563): lin0 (16 rows/block)
// blocks [1563,1628): Bt2 chunk kc = bid-1563 (coalesced We2/be2 stage -> coalesced write)
// blocks [1628,1884): zero agg/pooled + build fragment-major bf16 Wib/Whb/Wrb
// Bt2 fragment-major: idx = kc*4096 + (s*4+c)*512 + lane*8 + j  holds
// B[k=kc][i = s*32 + (lane>>4)*8 + j][o = c*16 + (lane&15)]  (kc=64 -> be2).
__global__ __launch_bounds__(256) void k_pre(const float* __restrict__ x,
                                             const float* __restrict__ W0,
                                             const float* __restrict__ b0,
                                             u16* __restrict__ x1b,
                                             const float* __restrict__ We2,
                                             const float* __restrict__ be2,
                                             float* __restrict__ agg,
                                             float* __restrict__ pooled,
                                             u16* __restrict__ Bt2,
                                             const float* __restrict__ Wi,
                                             const float* __restrict__ Wh,
                                             const float* __restrict__ Wroot,
                                             u16* __restrict__ Wib,
                                             u16* __restrict__ Whb,
                                             u16* __restrict__ Wrb) {
    __shared__ float sbuf[4096 + 512];
    int tid = threadIdx.x;
    if (blockIdx.x < 1563) {
        float* sW = sbuf;            // [FIN*DD] = 2048
        float* sx = sbuf + 4096;     // [16*FIN] = 512
        for (int i = tid; i < FIN * DD; i += 256) sW[i] = W0[i];
        int nbase = blockIdx.x * 16;
        for (int i = tid; i < 16 * FIN; i += 256) {
            int nl = i >> 5, f = i & 31;
            int n = nbase + nl;
            sx[i] = (n < NN) ? x[n * FIN + f] : 0.f;
        }
        __syncthreads();
        int lane = tid & 63, nl = tid >> 6;
        float bias = b0[lane];
        #pragma unroll
        for (int rr = 0; rr < 4; rr++) {
            int row = nl * 4 + rr;
            int n = nbase + row;
            if (n < NN) {
                float acc = bias;
                #pragma unroll
                for (int f = 0; f < FIN; f++) acc += sx[row * FIN + f] * sW[f * DD + lane];
                x1b[n * DD + lane] = f2b(fmaxf(acc, 0.f));
            }
        }
    } else if (blockIdx.x < 1628) {
        int kc = blockIdx.x - 1563;                 // [0,65)
        const float* src = (kc < 64) ? (We2 + kc * 4096) : be2;
        for (int i = tid; i < 4096; i += 256) sbuf[i] = src[i];
        __syncthreads();
        for (int m = tid; m < 4096; m += 256) {
            int f = m >> 9, ln = (m >> 3) & 63, j = m & 7;
            int s = f >> 2, c = f & 3;
            int o = c * 16 + (ln & 15);
            int rlow = s * 32 + (ln >> 4) * 8 + j;
            Bt2[kc * 4096 + m] = f2b(sbuf[rlow * 64 + o]);
        }
    } else {
        int tid0 = (blockIdx.x - 1628) * 256 + threadIdx.x;
        const int STR = 256 * 256;
        for (int i = tid0; i < NN * DD; i += STR) agg[i] = 0.f;
        for (int i = tid0; i < NG * DD; i += STR) pooled[i] = 0.f;
        for (int i = tid0; i < 12288; i += STR) {
            int fr = i >> 9, lane = (i >> 3) & 63, j = i & 7;
            int c = fr >> 1, kcx = fr & 1;
            int row = c * 16 + (lane & 15);
            int col = kcx * 32 + (lane >> 4) * 8 + j;
            Wib[i] = f2b(Wi[row * 64 + col]);
            Whb[i] = f2b(Wh[row * 64 + col]);
        }
        for (int i = tid0; i < 4096; i += STR) {
            int fr = i >> 9, lane = (i >> 3) & 63, j = i & 7;
            int c = fr >> 1, kcx = fr & 1;
            int row = c * 16 + (lane & 15);
            int col = kcx * 32 + (lane >> 4) * 8 + j;
            Wrb[i] = f2b(Wroot[col * 64 + row]);     // transposed (matches old staging)
        }
    }
}

// ---- fused NNConv message GEMM + scatter (round-3 verbatim: best measured 83.7us) --------
__global__ __launch_bounds__(512, 4) void k_msg(const float* __restrict__ ea,
                                                const int* __restrict__ eidx,
                                                const float* __restrict__ We1,
                                                const float* __restrict__ be1,
                                                const u16* __restrict__ x1b,
                                                const u16* __restrict__ Bt2,
                                                float* __restrict__ agg) {
    __shared__ __align__(16) u16 sX[128 * 72];   // gathered x1 rows (bf16), pad 72
    __shared__ __align__(16) float sT[65 * 128]; // t transposed [k][e], f32; row 64 = 1.0
    __shared__ float sWe1[8 * 64];
    __shared__ float sbe1[64];
    __shared__ int sDst[128];
    const int tid = threadIdx.x;
    const int lane = tid & 63, wv = tid >> 6;
    const int ll = lane & 15, quad = lane >> 4;
    const int rh = wv >> 2, cq = wv & 3;       // row-half, col-quarter
    const int e0 = blockIdx.x * 128;
    const bool i64 = idx_is_i64(eidx);

    if (tid < 512) sWe1[tid] = We1[tid];
    if (tid < 64) sbe1[tid] = be1[tid];
    if (tid < 128) {
        sDst[tid] = (e0 + tid < NE) ? ld_dst(eidx, e0 + tid, i64) : 0;
        sT[64 * 128 + tid] = 1.0f;             // bias chunk: t = 1
    }

    // phase 1: gather x1 rows (bf16) for 128 edges; each thread: 32 B of one row
    const int el4 = tid >> 2, seg = tid & 3;
    const int eg4 = e0 + el4;
    {
        if (eg4 < NE) {
            int sv = ld_src(eidx, eg4, i64);
            const u16* xr = x1b + sv * 64 + seg * 16;
            *(uint4*)&sX[el4 * 72 + seg * 16]     = *(const uint4*)(xr);
            *(uint4*)&sX[el4 * 72 + seg * 16 + 8] = *(const uint4*)(xr + 8);
        } else {
            uint4 z = make_uint4(0, 0, 0, 0);
            *(uint4*)&sX[el4 * 72 + seg * 16]     = z;
            *(uint4*)&sX[el4 * 72 + seg * 16 + 8] = z;
        }
    }
    float eav[8];
    if (eg4 < NE) {
        f32x4 v0 = *(const f32x4*)(ea + eg4 * 8);
        f32x4 v1 = *(const f32x4*)(ea + eg4 * 8 + 4);
        #pragma unroll
        for (int f = 0; f < 4; f++) { eav[f] = v0[f]; eav[4 + f] = v1[f]; }
    } else {
        #pragma unroll
        for (int f = 0; f < 8; f++) eav[f] = 0.f;
    }
    __syncthreads();

    // phase 2: t[e,k] = relu(ea @ We1 + be1); each thread: 16 k-values of its edge (f32)
    {
        int k0 = seg * 16;
        for (int kk = 0; kk < 16; kk++) {
            int k = k0 + kk;
            float acc = sbe1[k];
            #pragma unroll
            for (int f = 0; f < 8; f++) acc += eav[f] * sWe1[f * 64 + k];
            sT[k * 128 + el4] = (eg4 < NE) ? fmaxf(acc, 0.f) : 0.f;
        }
    }
    __syncthreads();   // last barrier — K-loop below is barrier-free

    // fixed A-fragments: this wave's 4 row-tiles (rows rh*64 .. rh*64+63)
    short8 xa[4][2];
    #pragma unroll
    for (int rt = 0; rt < 4; rt++)
        #pragma unroll
        for (int s = 0; s < 2; s++)
            xa[rt][s] = *(const short8*)&sX[(rh * 64 + rt * 16 + ll) * 72 + s * 32 + quad * 8];

    f32x4 msg[4];
    #pragma unroll
    for (int rt = 0; rt < 4; rt++) msg[rt] = (f32x4){0.f, 0.f, 0.f, 0.f};

    // coalesced per-lane B pointers for this wave's column quarter
    const u16* gB0 = Bt2 + (0 * 4 + cq) * 512 + lane * 8;
    const u16* gB1 = Bt2 + (1 * 4 + cq) * 512 + lane * 8;
    const f32x4 zero = (f32x4){0.f, 0.f, 0.f, 0.f};
    const int tkoff = rh * 64 + quad * 4;

    // pipeline prologue: B for kc 0,1 in flight; tk for kc 0 in regs
    short8 c00 = *(const short8*)(gB0);
    short8 c01 = *(const short8*)(gB1);
    short8 c10 = *(const short8*)(gB0 + 4096);
    short8 c11 = *(const short8*)(gB1 + 4096);
    f32x4 tkA[4], tkB[4];
    #pragma unroll
    for (int rt = 0; rt < 4; rt++)
        tkA[rt] = *(const f32x4*)&sT[tkoff + rt * 16];

    for (int kc = 0; kc < 62; kc += 2) {
        // prefetch B two kc ahead
        short8 n00 = *(const short8*)(gB0 + (kc + 2) * 4096);
        short8 n01 = *(const short8*)(gB1 + (kc + 2) * 4096);
        short8 n10 = *(const short8*)(gB0 + (kc + 3) * 4096);
        short8 n11 = *(const short8*)(gB1 + (kc + 3) * 4096);
        // prefetch tk one kc ahead
        #pragma unroll
        for (int rt = 0; rt < 4; rt++)
            tkB[rt] = *(const f32x4*)&sT[(kc + 1) * 128 + tkoff + rt * 16];
        // compute kc (independent q0,q1)
        #pragma unroll
        for (int rt = 0; rt < 4; rt++) {
            f32x4 q0 = __builtin_amdgcn_mfma_f32_16x16x32_bf16(xa[rt][0], c00, zero, 0, 0, 0);
            f32x4 q1 = __builtin_amdgcn_mfma_f32_16x16x32_bf16(xa[rt][1], c01, zero, 0, 0, 0);
            msg[rt] += tkA[rt] * q0;
            msg[rt] += tkA[rt] * q1;
        }
        #pragma unroll
        for (int rt = 0; rt < 4; rt++)
            tkA[rt] = *(const f32x4*)&sT[(kc + 2) * 128 + tkoff + rt * 16];
        // compute kc+1
        #pragma unroll
        for (int rt = 0; rt < 4; rt++) {
            f32x4 q0 = __builtin_amdgcn_mfma_f32_16x16x32_bf16(xa[rt][0], c10, zero, 0, 0, 0);
            f32x4 q1 = __builtin_amdgcn_mfma_f32_16x16x32_bf16(xa[rt][1], c11, zero, 0, 0, 0);
            msg[rt] += tkB[rt] * q0;
            msg[rt] += tkB[rt] * q1;
        }
        c00 = n00; c01 = n01; c10 = n10; c11 = n11;
    }
    // tail: kc = 62, 63 (in c*), then bias chunk 64 (prefetched into n0*)
    {
        short8 n00 = *(const short8*)(gB0 + 64 * 4096);
        short8 n01 = *(const short8*)(gB1 + 64 * 4096);
        #pragma unroll
        for (int rt = 0; rt < 4; rt++)
            tkB[rt] = *(const f32x4*)&sT[63 * 128 + tkoff + rt * 16];
        #pragma unroll
        for (int rt = 0; rt < 4; rt++) {
            f32x4 q0 = __builtin_amdgcn_mfma_f32_16x16x32_bf16(xa[rt][0], c00, zero, 0, 0, 0);
            f32x4 q1 = __builtin_amdgcn_mfma_f32_16x16x32_bf16(xa[rt][1], c01, zero, 0, 0, 0);
            msg[rt] += tkA[rt] * q0;
            msg[rt] += tkA[rt] * q1;
        }
        #pragma unroll
        for (int rt = 0; rt < 4; rt++)
            tkA[rt] = *(const f32x4*)&sT[64 * 128 + tkoff + rt * 16];  // = 1.0
        #pragma unroll
        for (int rt = 0; rt < 4; rt++) {
            f32x4 q0 = __builtin_amdgcn_mfma_f32_16x16x32_bf16(xa[rt][0], c10, zero, 0, 0, 0);
            f32x4 q1 = __builtin_amdgcn_mfma_f32_16x16x32_bf16(xa[rt][1], c11, zero, 0, 0, 0);
            msg[rt] += tkB[rt] * q0;
            msg[rt] += tkB[rt] * q1;
        }
        #pragma unroll
        for (int rt = 0; rt < 4; rt++) {
            f32x4 q0 = __builtin_amdgcn_mfma_f32_16x16x32_bf16(xa[rt][0], n00, zero, 0, 0, 0);
            f32x4 q1 = __builtin_amdgcn_mfma_f32_16x16x32_bf16(xa[rt][1], n01, zero, 0, 0, 0);
            msg[rt] += tkA[rt] * q0;
            msg[rt] += tkA[rt] * q1;
        }
    }

    // epilogue: row = rh*64 + rt*16 + quad*4 + r, col = cq*16 + ll; scatter into agg[dst]
    #pragma unroll
    for (int rt = 0; rt < 4; rt++) {
        #pragma unroll
        for (int r = 0; r < 4; r++) {
            int el = rh * 64 + rt * 16 + quad * 4 + r;
            int eg = e0 + el;
            if (eg < NE) {
                int d = sDst[el];
                atomicAdd(&agg[d * 64 + cq * 16 + ll], msg[rt][r]);
            }
        }
    }
}

// ---- GRU via MFMA: B-fragments direct from pre-built global bf16 buffers -----------------
// v2: no sWi/sWh staging (was 96KB f32 reads + 6144 cvt + 55KB LDS RT per block), no
// staging barriers. Wib/Whb/Wrb are L2-resident (24/24/8 KB), fragment-major:
// frag (c,kc) at [(c*2+kc)*512 + lane*8 .. +7]. LDS: 9216+16640+256 = 26KB.
__global__ __launch_bounds__(256) void k_gru(const u16* __restrict__ x1b,
                                             const float* __restrict__ agg,
                                             const u16* __restrict__ Wib,
                                             const u16* __restrict__ Whb,
                                             const u16* __restrict__ Wrb,
                                             const float* __restrict__ bconv,
                                             const float* __restrict__ bi,
                                             const float* __restrict__ bh,
                                             const int* __restrict__ batch,
                                             float* __restrict__ pooled) {
    __shared__ __align__(16) u16 sX2[64 * 72];
    __shared__ float hbuf[64 * 65];
    __shared__ int sBatch[64];
    const int tid = threadIdx.x;
    const int lane = tid & 63, wv = tid >> 6;
    const int ll = lane & 15, quad = lane >> 4;
    const int n0 = blockIdx.x * 64;

    if (tid < 64) {
        int n = n0 + tid;
        sBatch[tid] = (n < NN) ? batch[n] : -1;
    }

    short8 ha[2];
    {
        int n = n0 + wv * 16 + ll;
        #pragma unroll
        for (int kc = 0; kc < 2; kc++) {
            if (n < NN) ha[kc] = *(const short8*)(x1b + n * 64 + kc * 32 + quad * 8);
            else        ha[kc] = (short8){0,0,0,0,0,0,0,0};
        }
    }
    f32x4 acc1[4];
    #pragma unroll
    for (int c = 0; c < 4; c++) acc1[c] = (f32x4){0.f, 0.f, 0.f, 0.f};
    #pragma unroll
    for (int kc = 0; kc < 2; kc++) {
        #pragma unroll
        for (int c = 0; c < 4; c++) {
            short8 b = *(const short8*)&Wrb[(c * 2 + kc) * 512 + lane * 8];
            acc1[c] = __builtin_amdgcn_mfma_f32_16x16x32_bf16(ha[kc], b, acc1[c], 0, 0, 0);
        }
    }
    #pragma unroll
    for (int c = 0; c < 4; c++) {
        int col = c * 16 + ll;
        float bcv = bconv[col];
        #pragma unroll
        for (int r = 0; r < 4; r++) {
            int row = wv * 16 + quad * 4 + r;
            int n = n0 + row;
            float v = 0.f;
            if (n < NN) v = fmaxf(acc1[c][r] + agg[n * 64 + col] + bcv, 0.f);
            sX2[row * 72 + col] = f2b(v);
        }
    }
    __syncthreads();

    short8 xa[2];
    #pragma unroll
    for (int kc = 0; kc < 2; kc++)
        xa[kc] = *(const short8*)&sX2[(wv * 16 + ll) * 72 + kc * 32 + quad * 8];

    f32x4 agi[12], agh[12];
    #pragma unroll
    for (int c = 0; c < 12; c++) { agi[c] = (f32x4){0.f,0.f,0.f,0.f}; agh[c] = (f32x4){0.f,0.f,0.f,0.f}; }
    #pragma unroll
    for (int kc = 0; kc < 2; kc++) {
        #pragma unroll
        for (int c = 0; c < 12; c++) {
            short8 bi8 = *(const short8*)&Wib[(c * 2 + kc) * 512 + lane * 8];
            short8 bh8 = *(const short8*)&Whb[(c * 2 + kc) * 512 + lane * 8];
            agi[c] = __builtin_amdgcn_mfma_f32_16x16x32_bf16(xa[kc], bi8, agi[c], 0, 0, 0);
            agh[c] = __builtin_amdgcn_mfma_f32_16x16x32_bf16(ha[kc], bh8, agh[c], 0, 0, 0);
        }
    }

    float hnv[4][4];
    #pragma unroll
    for (int c0 = 0; c0 < 4; c0++) {
        int d = c0 * 16 + ll;
        float bir = bi[d],        bhr = bh[d];
        float biz = bi[64 + d],   bhz = bh[64 + d];
        float bin = bi[128 + d],  bhn = bh[128 + d];
        #pragma unroll
        for (int r = 0; r < 4; r++) {
            int row = wv * 16 + quad * 4 + r;
            int n = n0 + row;
            float gir = agi[c0][r] + bir,     ghr = agh[c0][r] + bhr;
            float giz = agi[c0 + 4][r] + biz, ghz = agh[c0 + 4][r] + bhz;
            float gin = agi[c0 + 8][r] + bin, ghn = agh[c0 + 8][r] + bhn;
            float rg = 1.f / (1.f + __expf(-(gir + ghr)));
            float zg = 1.f / (1.f + __expf(-(giz + ghz)));
            float ng = tanhf(gin + rg * ghn);
            float hv = (n < NN) ? b2f(x1b[n * 64 + d]) : 0.f;
            hnv[c0][r] = (n < NN) ? ((1.f - zg) * ng + zg * hv) : 0.f;
        }
    }
    __syncthreads();

    #pragma unroll
    for (int c0 = 0; c0 < 4; c0++) {
        int d = c0 * 16 + ll;
        #pragma unroll
        for (int r = 0; r < 4; r++) {
            int row = wv * 16 + quad * 4 + r;
            hbuf[row * 65 + d] = hnv[c0][r];
        }
    }
    __syncthreads();

    {
        int d = lane;
        float sum = 0.f;
        int pb = sBatch[wv * 16];
        #pragma unroll
        for (int rr = 0; rr < 16; rr++) {
            int row = wv * 16 + rr;
            int b = sBatch[row];
            float v = hbuf[row * 65 + d];
            if (b != pb) {
                if (pb >= 0) atomicAdd(&pooled[pb * 64 + d], sum);
                sum = v; pb = b;
            } else {
                sum += v;
            }
        }
        if (pb >= 0) atomicAdd(&pooled[pb * 64 + d], sum);
    }
}

// ---- heads: two 3-layer MLPs over pooled; output FLOAT32 ---------------------------------
__global__ __launch_bounds__(256) void k_heads(const float* __restrict__ pooled,
                                               const float* __restrict__ W11, const float* __restrict__ b11,
                                               const float* __restrict__ W12, const float* __restrict__ b12,
                                               const float* __restrict__ W13, const float* __restrict__ b13,
                                               const float* __restrict__ W21, const float* __restrict__ b21,
                                               const float* __restrict__ W22, const float* __restrict__ b22,
                                               const float* __restrict__ W23, const float* __restrict__ b23,
                                               float* __restrict__ out) {
    __shared__ float sV[4][64];
    __shared__ float sA[4][64];
    int tid = threadIdx.x, lane = tid & 63, wv = tid >> 6;
    int g = blockIdx.x * 4 + wv;
    if (g >= NG) return;
    float p = pooled[g * 64 + lane];
    sV[wv][lane] = p;
    float y[2];
    const float* W1s[2] = {W11, W21}; const float* b1s[2] = {b11, b21};
    const float* W2s[2] = {W12, W22}; const float* b2s[2] = {b12, b22};
    const float* W3s[2] = {W13, W23}; const float* b3s[2] = {b13, b23};
    #pragma unroll
    for (int hd = 0; hd < 2; hd++) {
        float a = b1s[hd][lane];
        #pragma unroll 8
        for (int i = 0; i < 64; i++) a += sV[wv][i] * W1s[hd][i * 64 + lane];
        a = fmaxf(a, 0.f);
        sA[wv][lane] = a;
        float a2 = b2s[hd][lane];
        #pragma unroll 8
        for (int i = 0; i < 64; i++) a2 += sA[wv][i] * W2s[hd][i * 64 + lane];
        a2 = fmaxf(a2, 0.f);
        float part = a2 * W3s[hd][lane];
        #pragma unroll
        for (int m = 32; m > 0; m >>= 1) part += __shfl_xor(part, m, 64);
        y[hd] = part + b3s[hd][0];
    }
    if (lane == 0) {
        out[g * 2 + 0] = y[0];
        out[g * 2 + 1] = y[1];
    }
}

extern "C" void kernel_launch(void* const* d_in, const int* in_sizes, int n_in,
                              void* d_out, int out_size, void* d_ws, size_t ws_size,
                              hipStream_t stream) {
    const float* x     = (const float*)d_in[0];
    const int* eidx    = (const int*)d_in[1];
    const float* ea    = (const float*)d_in[2];
    const int* batch   = (const int*)d_in[3];
    const float* W0    = (const float*)d_in[4];  const float* b0    = (const float*)d_in[5];
    const float* We1   = (const float*)d_in[6];  const float* be1   = (const float*)d_in[7];
    const float* We2   = (const float*)d_in[8];  const float* be2   = (const float*)d_in[9];
    const float* Wroot = (const float*)d_in[10]; const float* bconv = (const float*)d_in[11];
    const float* Wi    = (const float*)d_in[12]; const float* Wh    = (const float*)d_in[13];
    const float* bi    = (const float*)d_in[14]; const float* bh    = (const float*)d_in[15];
    const float* W11   = (const float*)d_in[16]; const float* b11   = (const float*)d_in[17];
    const float* W12   = (const float*)d_in[18]; const float* b12   = (const float*)d_in[19];
    const float* W13   = (const float*)d_in[20]; const float* b13   = (const float*)d_in[21];
    const float* W21   = (const float*)d_in[22]; const float* b21   = (const float*)d_in[23];
    const float* W22   = (const float*)d_in[24]; const float* b22   = (const float*)d_in[25];
    const float* W23   = (const float*)d_in[26]; const float* b23   = (const float*)d_in[27];
    float* out = (float*)d_out;

    // workspace: total 10,445,824 B
    char* ws = (char*)d_ws;
    float* agg    = (float*)(ws);                       // 6,400,000 B
    u16*   x1b    = (u16*)(ws + 6400000);               // 3,200,000 B
    u16*   Bt2    = (u16*)(ws + 9600000);               //   532,480 B
    float* pooled = (float*)(ws + 10132480);            //   256,000 B
    u16*   Wib    = (u16*)(ws + 10388480);              //    24,576 B
    u16*   Whb    = (u16*)(ws + 10413056);              //    24,576 B
    u16*   Wrb    = (u16*)(ws + 10437632);              //     8,192 B

    hipLaunchKernelGGL(k_pre, dim3(1884), dim3(256), 0, stream,
                       x, W0, b0, x1b, We2, be2, agg, pooled, Bt2,
                       Wi, Wh, Wroot, Wib, Whb, Wrb);
    hipLaunchKernelGGL(k_msg, dim3(782), dim3(512), 0, stream, ea, eidx, We1, be1, x1b, Bt2, agg);
    hipLaunchKernelGGL(k_gru, dim3(391), dim3(256), 0, stream, x1b, agg,
                       Wib, Whb, Wrb, bconv, bi, bh, batch, pooled);
    hipLaunchKernelGGL(k_heads, dim3(250), dim3(256), 0, stream, pooled,
                       W11, b11, W12, b12, W13, b13, W21, b21, W22, b22, W23, b23, out);
}

// Round 7
// 227.019 us; speedup vs baseline: 1.3362x; 1.0280x over previous
//
#include <hip/hip_runtime.h>
#include <hip/hip_bf16.h>
#include <hip/hip_fp16.h>

#define NN 25000
#define NE 100000
#define FIN 32
#define DD 64
#define NG 1000

typedef unsigned short u16;
typedef __attribute__((ext_vector_type(8))) short short8;
typedef __attribute__((ext_vector_type(8))) _Float16 f16x8;
typedef __attribute__((ext_vector_type(4))) float f32x4;

__device__ __forceinline__ u16 f2h(float f) {
    __half h = __float2half(f);
    return __builtin_bit_cast(u16, h);
}
__device__ __forceinline__ float h2f(u16 u) {
    __half h = __builtin_bit_cast(__half, u);
    return __half2float(h);
}
__device__ __forceinline__ f16x8 s2h(short8 v) { return __builtin_bit_cast(f16x8, v); }
// scale 8 f16 (packed in short8) by a replicated f16 scalar (4x v_pk_mul_f16)
__device__ __forceinline__ short8 scale8(short8 v, __half2 t) {
    union { short8 s; __half2 h[4]; } u; u.s = v;
    u.h[0] = __hmul2(u.h[0], t);
    u.h[1] = __hmul2(u.h[1], t);
    u.h[2] = __hmul2(u.h[2], t);
    u.h[3] = __hmul2(u.h[3], t);
    return u.s;
}
// edge_index may be int64 read as int32 words: odd words would all be 0.
__device__ __forceinline__ bool idx_is_i64(const int* e) {
    return (e[1] == 0) & (e[3] == 0) & (e[5] == 0) & (e[7] == 0) & (e[9] == 0);
}
__device__ __forceinline__ int ld_src(const int* e, int i, bool i64) {
    return i64 ? e[2 * i] : e[i];
}
__device__ __forceinline__ int ld_dst(const int* e, int i, bool i64) {
    return i64 ? e[2 * (NE + i)] : e[NE + i];
}

// ---- fused pre-pass (round-6 structure, outputs now FP16) --------------------------------
// blocks [0,1563): lin0 (16 rows/block) -> x1b f16
// blocks [1563,1628): Bt2 chunk kc = bid-1563 (coalesced We2/be2 stage -> coalesced write)
// blocks [1628,1884): zero agg/pooled + build fragment-major f16 Wib/Whb/Wrb
__global__ __launch_bounds__(256) void k_pre(const float* __restrict__ x,
                                             const float* __restrict__ W0,
                                             const float* __restrict__ b0,
                                             u16* __restrict__ x1b,
                                             const float* __restrict__ We2,
                                             const float* __restrict__ be2,
                                             float* __restrict__ agg,
                                             float* __restrict__ pooled,
                                             u16* __restrict__ Bt2,
                                             const float* __restrict__ Wi,
                                             const float* __restrict__ Wh,
                                             const float* __restrict__ Wroot,
                                             u16* __restrict__ Wib,
                                             u16* __restrict__ Whb,
                                             u16* __restrict__ Wrb) {
    __shared__ float sbuf[4096 + 512];
    int tid = threadIdx.x;
    if (blockIdx.x < 1563) {
        float* sW = sbuf;            // [FIN*DD] = 2048
        float* sx = sbuf + 4096;     // [16*FIN] = 512
        for (int i = tid; i < FIN * DD; i += 256) sW[i] = W0[i];
        int nbase = blockIdx.x * 16;
        for (int i = tid; i < 16 * FIN; i += 256) {
            int nl = i >> 5, f = i & 31;
            int n = nbase + nl;
            sx[i] = (n < NN) ? x[n * FIN + f] : 0.f;
        }
        __syncthreads();
        int lane = tid & 63, nl = tid >> 6;
        float bias = b0[lane];
        #pragma unroll
        for (int rr = 0; rr < 4; rr++) {
            int row = nl * 4 + rr;
            int n = nbase + row;
            if (n < NN) {
                float acc = bias;
                #pragma unroll
                for (int f = 0; f < FIN; f++) acc += sx[row * FIN + f] * sW[f * DD + lane];
                x1b[n * DD + lane] = f2h(fmaxf(acc, 0.f));
            }
        }
    } else if (blockIdx.x < 1628) {
        int kc = blockIdx.x - 1563;                 // [0,65)
        const float* src = (kc < 64) ? (We2 + kc * 4096) : be2;
        for (int i = tid; i < 4096; i += 256) sbuf[i] = src[i];
        __syncthreads();
        for (int m = tid; m < 4096; m += 256) {
            int f = m >> 9, ln = (m >> 3) & 63, j = m & 7;
            int s = f >> 2, c = f & 3;
            int o = c * 16 + (ln & 15);
            int rlow = s * 32 + (ln >> 4) * 8 + j;
            Bt2[kc * 4096 + m] = f2h(sbuf[rlow * 64 + o]);
        }
    } else {
        int tid0 = (blockIdx.x - 1628) * 256 + threadIdx.x;
        const int STR = 256 * 256;
        for (int i = tid0; i < NN * DD; i += STR) agg[i] = 0.f;
        for (int i = tid0; i < NG * DD; i += STR) pooled[i] = 0.f;
        for (int i = tid0; i < 12288; i += STR) {
            int fr = i >> 9, lane = (i >> 3) & 63, j = i & 7;
            int c = fr >> 1, kcx = fr & 1;
            int row = c * 16 + (lane & 15);
            int col = kcx * 32 + (lane >> 4) * 8 + j;
            Wib[i] = f2h(Wi[row * 64 + col]);
            Whb[i] = f2h(Wh[row * 64 + col]);
        }
        for (int i = tid0; i < 4096; i += STR) {
            int fr = i >> 9, lane = (i >> 3) & 63, j = i & 7;
            int c = fr >> 1, kcx = fr & 1;
            int row = c * 16 + (lane & 15);
            int col = kcx * 32 + (lane >> 4) * 8 + j;
            Wrb[i] = f2h(Wroot[col * 64 + row]);     // transposed (matches old staging)
        }
    }
}

// ---- fused NNConv message GEMM + scatter -------------------------------------------------
// v7 "scale-A": rounds 0-6 all read per-accumulator t from LDS: 64 B/thread/kc ->
// 64 KB/CU/kc ~ 770 cyc at measured b128 throughput == the entire kc budget at 84us.
// Fix: msg = sum_k (t[e,k]*x1[e]) @ W2[k] -- A-frag rows are lane-uniform, so the t-scale
// is ONE per-lane scalar: one swizzled ds_read_b128 per thread per kc (tq[rt] for 4 rt)
// + 8 v_pk_mul_f16, MFMA now C-accumulating (the 16 f32 FMAs of msg+=tk*q deleted).
// LDS K-loop traffic drops 4x. Whole x1/W2 path moves bf16->f16 (better mantissa).
__global__ __launch_bounds__(512, 4) void k_msg(const float* __restrict__ ea,
                                                const int* __restrict__ eidx,
                                                const float* __restrict__ We1,
                                                const float* __restrict__ be1,
                                                const u16* __restrict__ x1b,
                                                const u16* __restrict__ Bt2,
                                                float* __restrict__ agg) {
    __shared__ __align__(16) u16 sX[128 * 72];   // gathered x1 rows (f16), pad 72
    __shared__ __align__(16) float sT[65 * 128]; // t swizzled: [kc][rh*64 + (e&15)*4 + (e>>4)]
    __shared__ float sWe1[8 * 64];
    __shared__ float sbe1[64];
    __shared__ int sDst[128];
    const int tid = threadIdx.x;
    const int lane = tid & 63, wv = tid >> 6;
    const int ll = lane & 15, quad = lane >> 4;
    const int rh = wv >> 2, cq = wv & 3;       // row-half, col-quarter
    const int e0 = blockIdx.x * 128;
    const bool i64 = idx_is_i64(eidx);

    if (tid < 512) sWe1[tid] = We1[tid];
    if (tid < 64) sbe1[tid] = be1[tid];
    if (tid < 128) {
        sDst[tid] = (e0 + tid < NE) ? ld_dst(eidx, e0 + tid, i64) : 0;
        sT[64 * 128 + tid] = 1.0f;             // bias chunk: t = 1 (position-agnostic)
    }

    // phase 1: gather x1 rows (f16) for 128 edges; each thread: 32 B of one row
    const int el4 = tid >> 2, seg = tid & 3;
    const int eg4 = e0 + el4;
    {
        if (eg4 < NE) {
            int sv = ld_src(eidx, eg4, i64);
            const u16* xr = x1b + sv * 64 + seg * 16;
            *(uint4*)&sX[el4 * 72 + seg * 16]     = *(const uint4*)(xr);
            *(uint4*)&sX[el4 * 72 + seg * 16 + 8] = *(const uint4*)(xr + 8);
        } else {
            uint4 z = make_uint4(0, 0, 0, 0);
            *(uint4*)&sX[el4 * 72 + seg * 16]     = z;
            *(uint4*)&sX[el4 * 72 + seg * 16 + 8] = z;
        }
    }
    float eav[8];
    if (eg4 < NE) {
        f32x4 v0 = *(const f32x4*)(ea + eg4 * 8);
        f32x4 v1 = *(const f32x4*)(ea + eg4 * 8 + 4);
        #pragma unroll
        for (int f = 0; f < 4; f++) { eav[f] = v0[f]; eav[4 + f] = v1[f]; }
    } else {
        #pragma unroll
        for (int f = 0; f < 8; f++) eav[f] = 0.f;
    }
    __syncthreads();

    // phase 2: t[e,k] = relu(ea @ We1 + be1), written SWIZZLED so the K-loop reads
    // tq for 4 rt as one f32x4: pos(e) = (e>>6)*64 + (e&15)*4 + ((e&63)>>4)
    {
        int eh = el4 & 63;
        const int tpos = (el4 >> 6) * 64 + (eh & 15) * 4 + (eh >> 4);
        int k0 = seg * 16;
        for (int kk = 0; kk < 16; kk++) {
            int k = k0 + kk;
            float acc = sbe1[k];
            #pragma unroll
            for (int f = 0; f < 8; f++) acc += eav[f] * sWe1[f * 64 + k];
            sT[k * 128 + tpos] = (eg4 < NE) ? fmaxf(acc, 0.f) : 0.f;
        }
    }
    __syncthreads();   // last barrier — K-loop below is barrier-free

    // fixed A-fragments: this wave's 4 row-tiles (rows rh*64 .. rh*64+63)
    short8 xa[4][2];
    #pragma unroll
    for (int rt = 0; rt < 4; rt++)
        #pragma unroll
        for (int s = 0; s < 2; s++)
            xa[rt][s] = *(const short8*)&sX[(rh * 64 + rt * 16 + ll) * 72 + s * 32 + quad * 8];

    f32x4 acc[4];
    #pragma unroll
    for (int rt = 0; rt < 4; rt++) acc[rt] = (f32x4){0.f, 0.f, 0.f, 0.f};

    // coalesced per-lane B pointers for this wave's column quarter
    const u16* gB0 = Bt2 + (0 * 4 + cq) * 512 + lane * 8;
    const u16* gB1 = Bt2 + (1 * 4 + cq) * 512 + lane * 8;

    short8 c0 = *(const short8*)(gB0);
    short8 c1 = *(const short8*)(gB1);

    for (int kc = 0; kc < 65; kc++) {
        int kn = (kc < 64) ? kc + 1 : 64;
        short8 n0 = *(const short8*)(gB0 + kn * 4096);
        short8 n1 = *(const short8*)(gB1 + kn * 4096);
        f32x4 tq = *(const f32x4*)&sT[kc * 128 + rh * 64 + ll * 4];
        f16x8 b0 = s2h(c0), b1 = s2h(c1);
        #pragma unroll
        for (int rt = 0; rt < 4; rt++) {
            __half2 th = __float2half2_rn(tq[rt]);
            f16x8 a0 = s2h(scale8(xa[rt][0], th));
            f16x8 a1 = s2h(scale8(xa[rt][1], th));
            acc[rt] = __builtin_amdgcn_mfma_f32_16x16x32_f16(a0, b0, acc[rt], 0, 0, 0);
            acc[rt] = __builtin_amdgcn_mfma_f32_16x16x32_f16(a1, b1, acc[rt], 0, 0, 0);
        }
        c0 = n0; c1 = n1;
    }

    // epilogue: row = rh*64 + rt*16 + quad*4 + r, col = cq*16 + ll; scatter into agg[dst]
    #pragma unroll
    for (int rt = 0; rt < 4; rt++) {
        #pragma unroll
        for (int r = 0; r < 4; r++) {
            int el = rh * 64 + rt * 16 + quad * 4 + r;
            int eg = e0 + el;
            if (eg < NE) {
                int d = sDst[el];
                atomicAdd(&agg[d * 64 + cq * 16 + ll], acc[rt][r]);
            }
        }
    }
}

// ---- GRU via MFMA (round-6 structure, f16 path) ------------------------------------------
__global__ __launch_bounds__(256) void k_gru(const u16* __restrict__ x1b,
                                             const float* __restrict__ agg,
                                             const u16* __restrict__ Wib,
                                             const u16* __restrict__ Whb,
                                             const u16* __restrict__ Wrb,
                                             const float* __restrict__ bconv,
                                             const float* __restrict__ bi,
                                             const float* __restrict__ bh,
                                             const int* __restrict__ batch,
                                             float* __restrict__ pooled) {
    __shared__ __align__(16) u16 sX2[64 * 72];
    __shared__ float hbuf[64 * 65];
    __shared__ int sBatch[64];
    const int tid = threadIdx.x;
    const int lane = tid & 63, wv = tid >> 6;
    const int ll = lane & 15, quad = lane >> 4;
    const int n0 = blockIdx.x * 64;

    if (tid < 64) {
        int n = n0 + tid;
        sBatch[tid] = (n < NN) ? batch[n] : -1;
    }

    short8 ha[2];
    {
        int n = n0 + wv * 16 + ll;
        #pragma unroll
        for (int kc = 0; kc < 2; kc++) {
            if (n < NN) ha[kc] = *(const short8*)(x1b + n * 64 + kc * 32 + quad * 8);
            else        ha[kc] = (short8){0,0,0,0,0,0,0,0};
        }
    }
    f32x4 acc1[4];
    #pragma unroll
    for (int c = 0; c < 4; c++) acc1[c] = (f32x4){0.f, 0.f, 0.f, 0.f};
    #pragma unroll
    for (int kc = 0; kc < 2; kc++) {
        #pragma unroll
        for (int c = 0; c < 4; c++) {
            short8 b = *(const short8*)&Wrb[(c * 2 + kc) * 512 + lane * 8];
            acc1[c] = __builtin_amdgcn_mfma_f32_16x16x32_f16(s2h(ha[kc]), s2h(b), acc1[c], 0, 0, 0);
        }
    }
    #pragma unroll
    for (int c = 0; c < 4; c++) {
        int col = c * 16 + ll;
        float bcv = bconv[col];
        #pragma unroll
        for (int r = 0; r < 4; r++) {
            int row = wv * 16 + quad * 4 + r;
            int n = n0 + row;
            float v = 0.f;
            if (n < NN) v = fmaxf(acc1[c][r] + agg[n * 64 + col] + bcv, 0.f);
            sX2[row * 72 + col] = f2h(v);
        }
    }
    __syncthreads();

    short8 xa[2];
    #pragma unroll
    for (int kc = 0; kc < 2; kc++)
        xa[kc] = *(const short8*)&sX2[(wv * 16 + ll) * 72 + kc * 32 + quad * 8];

    f32x4 agi[12], agh[12];
    #pragma unroll
    for (int c = 0; c < 12; c++) { agi[c] = (f32x4){0.f,0.f,0.f,0.f}; agh[c] = (f32x4){0.f,0.f,0.f,0.f}; }
    #pragma unroll
    for (int kc = 0; kc < 2; kc++) {
        #pragma unroll
        for (int c = 0; c < 12; c++) {
            short8 bi8 = *(const short8*)&Wib[(c * 2 + kc) * 512 + lane * 8];
            short8 bh8 = *(const short8*)&Whb[(c * 2 + kc) * 512 + lane * 8];
            agi[c] = __builtin_amdgcn_mfma_f32_16x16x32_f16(s2h(xa[kc]), s2h(bi8), agi[c], 0, 0, 0);
            agh[c] = __builtin_amdgcn_mfma_f32_16x16x32_f16(s2h(ha[kc]), s2h(bh8), agh[c], 0, 0, 0);
        }
    }

    float hnv[4][4];
    #pragma unroll
    for (int c0 = 0; c0 < 4; c0++) {
        int d = c0 * 16 + ll;
        float bir = bi[d],        bhr = bh[d];
        float biz = bi[64 + d],   bhz = bh[64 + d];
        float bin = bi[128 + d],  bhn = bh[128 + d];
        #pragma unroll
        for (int r = 0; r < 4; r++) {
            int row = wv * 16 + quad * 4 + r;
            int n = n0 + row;
            float gir = agi[c0][r] + bir,     ghr = agh[c0][r] + bhr;
            float giz = agi[c0 + 4][r] + biz, ghz = agh[c0 + 4][r] + bhz;
            float gin = agi[c0 + 8][r] + bin, ghn = agh[c0 + 8][r] + bhn;
            float rg = 1.f / (1.f + __expf(-(gir + ghr)));
            float zg = 1.f / (1.f + __expf(-(giz + ghz)));
            float ng = tanhf(gin + rg * ghn);
            float hv = (n < NN) ? h2f(x1b[n * 64 + d]) : 0.f;
            hnv[c0][r] = (n < NN) ? ((1.f - zg) * ng + zg * hv) : 0.f;
        }
    }
    __syncthreads();

    #pragma unroll
    for (int c0 = 0; c0 < 4; c0++) {
        int d = c0 * 16 + ll;
        #pragma unroll
        for (int r = 0; r < 4; r++) {
            int row = wv * 16 + quad * 4 + r;
            hbuf[row * 65 + d] = hnv[c0][r];
        }
    }
    __syncthreads();

    {
        int d = lane;
        float sum = 0.f;
        int pb = sBatch[wv * 16];
        #pragma unroll
        for (int rr = 0; rr < 16; rr++) {
            int row = wv * 16 + rr;
            int b = sBatch[row];
            float v = hbuf[row * 65 + d];
            if (b != pb) {
                if (pb >= 0) atomicAdd(&pooled[pb * 64 + d], sum);
                sum = v; pb = b;
            } else {
                sum += v;
            }
        }
        if (pb >= 0) atomicAdd(&pooled[pb * 64 + d], sum);
    }
}

// ---- heads: two 3-layer MLPs over pooled; output FLOAT32 ---------------------------------
__global__ __launch_bounds__(256) void k_heads(const float* __restrict__ pooled,
                                               const float* __restrict__ W11, const float* __restrict__ b11,
                                               const float* __restrict__ W12, const float* __restrict__ b12,
                                               const float* __restrict__ W13, const float* __restrict__ b13,
                                               const float* __restrict__ W21, const float* __restrict__ b21,
                                               const float* __restrict__ W22, const float* __restrict__ b22,
                                               const float* __restrict__ W23, const float* __restrict__ b23,
                                               float* __restrict__ out) {
    __shared__ float sV[4][64];
    __shared__ float sA[4][64];
    int tid = threadIdx.x, lane = tid & 63, wv = tid >> 6;
    int g = blockIdx.x * 4 + wv;
    if (g >= NG) return;
    float p = pooled[g * 64 + lane];
    sV[wv][lane] = p;
    float y[2];
    const float* W1s[2] = {W11, W21}; const float* b1s[2] = {b11, b21};
    const float* W2s[2] = {W12, W22}; const float* b2s[2] = {b12, b22};
    const float* W3s[2] = {W13, W23}; const float* b3s[2] = {b13, b23};
    #pragma unroll
    for (int hd = 0; hd < 2; hd++) {
        float a = b1s[hd][lane];
        #pragma unroll 8
        for (int i = 0; i < 64; i++) a += sV[wv][i] * W1s[hd][i * 64 + lane];
        a = fmaxf(a, 0.f);
        sA[wv][lane] = a;
        float a2 = b2s[hd][lane];
        #pragma unroll 8
        for (int i = 0; i < 64; i++) a2 += sA[wv][i] * W2s[hd][i * 64 + lane];
        a2 = fmaxf(a2, 0.f);
        float part = a2 * W3s[hd][lane];
        #pragma unroll
        for (int m = 32; m > 0; m >>= 1) part += __shfl_xor(part, m, 64);
        y[hd] = part + b3s[hd][0];
    }
    if (lane == 0) {
        out[g * 2 + 0] = y[0];
        out[g * 2 + 1] = y[1];
    }
}

extern "C" void kernel_launch(void* const* d_in, const int* in_sizes, int n_in,
                              void* d_out, int out_size, void* d_ws, size_t ws_size,
                              hipStream_t stream) {
    const float* x     = (const float*)d_in[0];
    const int* eidx    = (const int*)d_in[1];
    const float* ea    = (const float*)d_in[2];
    const int* batch   = (const int*)d_in[3];
    const float* W0    = (const float*)d_in[4];  const float* b0    = (const float*)d_in[5];
    const float* We1   = (const float*)d_in[6];  const float* be1   = (const float*)d_in[7];
    const float* We2   = (const float*)d_in[8];  const float* be2   = (const float*)d_in[9];
    const float* Wroot = (const float*)d_in[10]; const float* bconv = (const float*)d_in[11];
    const float* Wi    = (const float*)d_in[12]; const float* Wh    = (const float*)d_in[13];
    const float* bi    = (const float*)d_in[14]; const float* bh    = (const float*)d_in[15];
    const float* W11   = (const float*)d_in[16]; const float* b11   = (const float*)d_in[17];
    const float* W12   = (const float*)d_in[18]; const float* b12   = (const float*)d_in[19];
    const float* W13   = (const float*)d_in[20]; const float* b13   = (const float*)d_in[21];
    const float* W21   = (const float*)d_in[22]; const float* b21   = (const float*)d_in[23];
    const float* W22   = (const float*)d_in[24]; const float* b22   = (const float*)d_in[25];
    const float* W23   = (const float*)d_in[26]; const float* b23   = (const float*)d_in[27];
    float* out = (float*)d_out;

    // workspace: total 10,445,824 B
    char* ws = (char*)d_ws;
    float* agg    = (float*)(ws);                       // 6,400,000 B
    u16*   x1b    = (u16*)(ws + 6400000);               // 3,200,000 B
    u16*   Bt2    = (u16*)(ws + 9600000);               //   532,480 B
    float* pooled = (float*)(ws + 10132480);            //   256,000 B
    u16*   Wib    = (u16*)(ws + 10388480);              //    24,576 B
    u16*   Whb    = (u16*)(ws + 10413056);              //    24,576 B
    u16*   Wrb    = (u16*)(ws + 10437632);              //     8,192 B

    hipLaunchKernelGGL(k_pre, dim3(1884), dim3(256), 0, stream,
                       x, W0, b0, x1b, We2, be2, agg, pooled, Bt2,
                       Wi, Wh, Wroot, Wib, Whb, Wrb);
    hipLaunchKernelGGL(k_msg, dim3(782), dim3(512), 0, stream, ea, eidx, We1, be1, x1b, Bt2, agg);
    hipLaunchKernelGGL(k_gru, dim3(391), dim3(256), 0, stream, x1b, agg,
                       Wib, Whb, Wrb, bconv, bi, bh, batch, pooled);
    hipLaunchKernelGGL(k_heads, dim3(250), dim3(256), 0, stream, pooled,
                       W11, b11, W12, b12, W13, b13, W21, b21, W22, b22, W23, b23, out);
}